// Round 5
// baseline (596.636 us; speedup 1.0000x reference)
//
#include <hip/hip_runtime.h>

#define N_NODES 100000
#define N_EDGES 600000
#define NCHUNK 98            // ceil(100000/1024)
#define LDS_STRIDE 136       // ushorts per row: 128 + 8 pad

typedef __attribute__((ext_vector_type(8))) short short8;
typedef __attribute__((ext_vector_type(4))) float f32x4;
typedef __attribute__((ext_vector_type(2))) unsigned short ushort2v;
typedef __attribute__((ext_vector_type(8))) unsigned short ushort8v;

__device__ __forceinline__ unsigned short f2b(float f) {   // fp32 -> bf16 RNE
    unsigned u = __builtin_bit_cast(unsigned, f);
    return (unsigned short)((u + 0x7fffu + ((u >> 16) & 1u)) >> 16);
}
__device__ __forceinline__ float b2f(unsigned short b) {
    return __builtin_bit_cast(float, (unsigned)b << 16);
}

// ---------------------------------------------------------------------------
__global__ void count_kernel(const int* __restrict__ e0, const int* __restrict__ e1,
                             const int* __restrict__ e2, int* __restrict__ cnt) {
    int e = blockIdx.x * blockDim.x + threadIdx.x;
    if (e >= N_EDGES) return;
    int r = blockIdx.y;
    const int* ei = (r == 0) ? e0 : (r == 1 ? e1 : e2);
    atomicAdd(&cnt[r * N_NODES + ei[N_EDGES + e]], 1);
}

// ---------------------------------------------------------------------------
__global__ __launch_bounds__(1024) void scan1_kernel(const int* __restrict__ cnt,
                                                     int* __restrict__ rowstart,
                                                     int* __restrict__ blocksum) {
    int r = blockIdx.y;
    int tid = threadIdx.x, lane = tid & 63, wid = tid >> 6;
    int i = blockIdx.x * 1024 + tid;
    __shared__ int wsum[16];
    int v = (i < N_NODES) ? cnt[r * N_NODES + i] : 0;
    int incl = v;
#pragma unroll
    for (int off = 1; off < 64; off <<= 1) {
        int t = __shfl_up(incl, off);
        if (lane >= off) incl += t;
    }
    if (lane == 63) wsum[wid] = incl;
    __syncthreads();
    if (wid == 0) {
        int wv = (lane < 16) ? wsum[lane] : 0;
#pragma unroll
        for (int off = 1; off < 16; off <<= 1) {
            int t = __shfl_up(wv, off);
            if (lane >= off) wv += t;
        }
        if (lane < 16) wsum[lane] = wv;
    }
    __syncthreads();
    int woff = (wid > 0) ? wsum[wid - 1] : 0;
    if (i < N_NODES) rowstart[r * N_NODES + i] = woff + incl - v;
    if (tid == 0) blocksum[r * NCHUNK + blockIdx.x] = wsum[15];
}

__global__ __launch_bounds__(128) void scan2_kernel(int* __restrict__ blocksum) {
    __shared__ int s[3 * NCHUNK];
    int tid = threadIdx.x;
    for (int i = tid; i < 3 * NCHUNK; i += 128) s[i] = blocksum[i];
    __syncthreads();
    if (tid < 3) {
        int run = 0;
        for (int j = 0; j < NCHUNK; j++) { int t = s[tid * NCHUNK + j]; s[tid * NCHUNK + j] = run; run += t; }
    }
    __syncthreads();
    for (int i = tid; i < 3 * NCHUNK; i += 128) blocksum[i] = s[i];
}

// Phase 3: add block offsets; also seed cursor = rowstart (absolute positions).
__global__ void scan3_kernel(int* __restrict__ rowstart, const int* __restrict__ blocksum,
                             int* __restrict__ cursor) {
    int r = blockIdx.y;
    int i = blockIdx.x * 256 + threadIdx.x;
    if (i < N_NODES) {
        int v = rowstart[r * N_NODES + i] + blocksum[r * NCHUNK + (i >> 10)];
        rowstart[r * N_NODES + i] = v;
        cursor[r * N_NODES + i] = v;
    }
}

// ---------------------------------------------------------------------------
// CSR fill: cursor holds absolute write positions (seeded from rowstart).
__global__ void fill_kernel(const int* __restrict__ e0, const int* __restrict__ e1,
                            const int* __restrict__ e2,
                            int* __restrict__ cursor, int* __restrict__ adj) {
    int e = blockIdx.x * blockDim.x + threadIdx.x;
    if (e >= N_EDGES) return;
    int r = blockIdx.y;
    const int* ei = (r == 0) ? e0 : (r == 1 ? e1 : e2);
    int src = ei[e], dst = ei[N_EDGES + e];
    int pos = atomicAdd(&cursor[r * N_NODES + dst], 1);
    adj[(size_t)r * N_EDGES + pos] = src;
}

// ---------------------------------------------------------------------------
// x (fp32) -> xb (bf16), 8 elems/thread.
__global__ void xcast_kernel(const float* __restrict__ x, unsigned short* __restrict__ xb) {
    int idx = blockIdx.x * 256 + threadIdx.x;
    const float4* p = (const float4*)x + (size_t)idx * 2;
    float4 a = p[0], b = p[1];
    ushort8v o;
    o[0] = f2b(a.x); o[1] = f2b(a.y); o[2] = f2b(a.z); o[3] = f2b(a.w);
    o[4] = f2b(b.x); o[5] = f2b(b.y); o[6] = f2b(b.z); o[7] = f2b(b.w);
    *(ushort8v*)(xb + (size_t)idx * 8) = o;
}

// ---------------------------------------------------------------------------
// Pre-swizzle weights into MFMA B-fragment order (coalesced lane*16B bursts).
__global__ void wprep_kernel(const float* __restrict__ Wl, const float* __restrict__ Wr,
                             const float* __restrict__ Wl_f, const float* __restrict__ Wr_f,
                             unsigned short* __restrict__ Wfrag, unsigned short* __restrict__ Wfrag2) {
    int idx = blockIdx.x * 256 + threadIdx.x;      // 448 blocks = 114688 threads
    int j = idx & 7, lane = (idx >> 3) & 63;
    int quad = lane >> 4, l16 = lane & 15;
    if (idx < 98304) {
        int t = (idx >> 9) & 1, s = (idx >> 10) & 7, w = (idx >> 13) & 3, r = idx >> 15;
        int k = s * 32 + quad * 8 + j;
        int n = w * 32 + t * 16 + l16;
        float v = (k < 128) ? Wl[((size_t)r * 128 + k) * 128 + n]
                            : Wr[((size_t)r * 128 + (k - 128)) * 128 + n];
        Wfrag[idx] = f2b(v);
    } else {
        int i2 = idx - 98304;
        if (i2 < 16384) {
            int t = (i2 >> 9) & 1, s = (i2 >> 10) & 3, w = (i2 >> 12) & 3;
            int k = s * 32 + quad * 8 + j;
            int n = w * 32 + t * 16 + l16;
            float v = (n < 64) ? Wl_f[(size_t)k * 64 + n] : Wr_f[(size_t)k * 64 + (n - 64)];
            Wfrag2[i2] = f2b(v);
        }
    }
}

// ---------------------------------------------------------------------------
// Fused per-64-row-tile: for r in 0..2 { gather agg_r into LDS, MFMA
// [agg|x](K=256)@Wfrag_r, hacc += relu(.+bl)/3 }, then h->LDS, layer-2
// MFMA h@Wfrag2 (K=128), write hWlb (cols 0..63) and out=hWr+bl_f (64..127).
// Wave w owns cols [w*32, w*32+32) and gathers LDS rows [w*16, w*16+16).
__global__ __launch_bounds__(256, 4) void mega2_kernel(
    const unsigned short* __restrict__ xb,
    const int* __restrict__ adj, const int* __restrict__ rowstart,
    const int* __restrict__ cnt,
    const unsigned short* __restrict__ Wfrag, const float* __restrict__ bl,
    const unsigned short* __restrict__ Wfrag2, const float* __restrict__ bl_f,
    unsigned short* __restrict__ hWlb, float* __restrict__ out) {
    __shared__ unsigned short s_x[64 * LDS_STRIDE];
    __shared__ unsigned short s_a[64 * LDS_STRIDE];   // agg tile, later reused for h
    int tid = threadIdx.x, wave = tid >> 6, lane = tid & 63;
    int quad = lane >> 4, l16 = lane & 15;
    int rowbase = blockIdx.x * 64;

    // stage x tile (bf16, coalesced)
#pragma unroll
    for (int it = 0; it < 4; it++) {
        int idx = tid + it * 256;
        int row = idx >> 4, c = idx & 15;
        int grow = rowbase + row;
        short8 xv = {0, 0, 0, 0, 0, 0, 0, 0};
        if (grow < N_NODES) xv = *(const short8*)(xb + (size_t)grow * 128 + c * 8);
        *(short8*)&s_x[row * LDS_STRIDE + c * 8] = xv;
    }

    float hacc[4][2][4];
#pragma unroll
    for (int g = 0; g < 4; g++)
#pragma unroll
        for (int t = 0; t < 2; t++)
#pragma unroll
            for (int q = 0; q < 4; q++) hacc[g][t][q] = 0.f;

    for (int r = 0; r < 3; r++) {
        if (r) __syncthreads();            // prior MFMA reads of s_a complete
        const int* adjr = adj + (size_t)r * N_EDGES;
        const int* rsr  = rowstart + r * N_NODES;
        const int* cntr = cnt + r * N_NODES;
        // gather-mean 16 rows for this wave directly into LDS
        for (int n = 0; n < 16; n++) {
            int lrow = wave * 16 + n;
            int node = rowbase + lrow;
            float ax = 0.f, ay = 0.f;
            int deg = 0;
            if (node < N_NODES) {
                int start = rsr[node];
                deg = cntr[node];
                int j = 0;
                for (; j + 4 <= deg; j += 4) {
                    int s0 = adjr[start + j],     s1 = adjr[start + j + 1];
                    int s2 = adjr[start + j + 2], s3 = adjr[start + j + 3];
                    ushort2v v0 = *(const ushort2v*)(xb + (size_t)s0 * 128 + lane * 2);
                    ushort2v v1 = *(const ushort2v*)(xb + (size_t)s1 * 128 + lane * 2);
                    ushort2v v2 = *(const ushort2v*)(xb + (size_t)s2 * 128 + lane * 2);
                    ushort2v v3 = *(const ushort2v*)(xb + (size_t)s3 * 128 + lane * 2);
                    ax += b2f(v0.x) + b2f(v1.x) + b2f(v2.x) + b2f(v3.x);
                    ay += b2f(v0.y) + b2f(v1.y) + b2f(v2.y) + b2f(v3.y);
                }
                for (; j < deg; j++) {
                    int s = adjr[start + j];
                    ushort2v v = *(const ushort2v*)(xb + (size_t)s * 128 + lane * 2);
                    ax += b2f(v.x); ay += b2f(v.y);
                }
            }
            float inv = 1.0f / fmaxf((float)deg, 1.0f);
            ushort2v o; o.x = f2b(ax * inv); o.y = f2b(ay * inv);
            *(ushort2v*)&s_a[lrow * LDS_STRIDE + lane * 2] = o;
        }
        __syncthreads();                   // covers s_x staging on r=0 too

        f32x4 acc[4][2];
#pragma unroll
        for (int g = 0; g < 4; g++) { acc[g][0] = (f32x4){0.f,0.f,0.f,0.f}; acc[g][1] = (f32x4){0.f,0.f,0.f,0.f}; }

        const unsigned short* W = Wfrag + r * 32768 + wave * 8192;
#pragma unroll
        for (int s = 0; s < 8; s++) {
            short8 bf0 = *(const short8*)(W + s * 1024 + lane * 8);      // coalesced 1KB
            short8 bf1 = *(const short8*)(W + s * 1024 + 512 + lane * 8);
            const unsigned short* src = (s < 4) ? s_a : s_x;
            int ko = (s & 3) * 32 + quad * 8;
#pragma unroll
            for (int g = 0; g < 4; g++) {
                short8 af = *(const short8*)&src[(g * 16 + l16) * LDS_STRIDE + ko];
                acc[g][0] = __builtin_amdgcn_mfma_f32_16x16x32_bf16(af, bf0, acc[g][0], 0, 0, 0);
                acc[g][1] = __builtin_amdgcn_mfma_f32_16x16x32_bf16(af, bf1, acc[g][1], 0, 0, 0);
            }
        }
        float b0 = bl[r * 128 + wave * 32 + l16];
        float b1 = bl[r * 128 + wave * 32 + 16 + l16];
#pragma unroll
        for (int g = 0; g < 4; g++)
#pragma unroll
            for (int t = 0; t < 2; t++) {
                float bb = t ? b1 : b0;
#pragma unroll
                for (int q = 0; q < 4; q++)
                    hacc[g][t][q] += fmaxf(acc[g][t][q] + bb, 0.f) * (1.0f / 3.0f);
            }
    }

    __syncthreads();                       // all MFMA reads of s_a/s_x done
    // h (C-layout regs) -> s_a (reused) as bf16 row-major
#pragma unroll
    for (int g = 0; g < 4; g++)
#pragma unroll
        for (int t = 0; t < 2; t++)
#pragma unroll
            for (int q = 0; q < 4; q++) {
                int lrow = g * 16 + quad * 4 + q;
                int col = wave * 32 + t * 16 + l16;
                s_a[lrow * LDS_STRIDE + col] = f2b(hacc[g][t][q]);
            }
    __syncthreads();

    // layer 2: h @ Wfrag2 (K=128)
    f32x4 acc2[4][2];
#pragma unroll
    for (int g = 0; g < 4; g++) { acc2[g][0] = (f32x4){0.f,0.f,0.f,0.f}; acc2[g][1] = (f32x4){0.f,0.f,0.f,0.f}; }
    const unsigned short* W2 = Wfrag2 + wave * 4096;
#pragma unroll
    for (int s = 0; s < 4; s++) {
        short8 bf0 = *(const short8*)(W2 + s * 1024 + lane * 8);
        short8 bf1 = *(const short8*)(W2 + s * 1024 + 512 + lane * 8);
        int ko = s * 32 + quad * 8;
#pragma unroll
        for (int g = 0; g < 4; g++) {
            short8 af = *(const short8*)&s_a[(g * 16 + l16) * LDS_STRIDE + ko];
            acc2[g][0] = __builtin_amdgcn_mfma_f32_16x16x32_bf16(af, bf0, acc2[g][0], 0, 0, 0);
            acc2[g][1] = __builtin_amdgcn_mfma_f32_16x16x32_bf16(af, bf1, acc2[g][1], 0, 0, 0);
        }
    }

#pragma unroll
    for (int g = 0; g < 4; g++)
#pragma unroll
        for (int t = 0; t < 2; t++) {
            int col = wave * 32 + t * 16 + l16;
#pragma unroll
            for (int q = 0; q < 4; q++) {
                int row = rowbase + g * 16 + quad * 4 + q;
                if (row < N_NODES) {
                    if (col < 64) hWlb[(size_t)row * 64 + col] = f2b(acc2[g][t][q]);
                    else out[(size_t)row * 64 + (col - 64)] = acc2[g][t][q] + bl_f[col - 64];
                }
            }
        }
}

// ---------------------------------------------------------------------------
// Gather-mean of hWl (bf16, 64 ch) + add into out (holds hWr + bl_f).
__global__ void gather64_kernel(const unsigned short* __restrict__ hWlb, const int* __restrict__ adj,
                                const int* __restrict__ rowstart, const int* __restrict__ cnt,
                                float* __restrict__ out) {
    int node = (blockIdx.x * blockDim.x + threadIdx.x) >> 6;
    int lane = threadIdx.x & 63;
    if (node >= N_NODES) return;
    int start = rowstart[node];
    int deg = cnt[node];
    float a = 0.f;
    int j = 0;
    for (; j + 4 <= deg; j += 4) {
        int s0 = adj[start + j], s1 = adj[start + j + 1];
        int s2 = adj[start + j + 2], s3 = adj[start + j + 3];
        a += b2f(hWlb[(size_t)s0 * 64 + lane]) + b2f(hWlb[(size_t)s1 * 64 + lane])
           + b2f(hWlb[(size_t)s2 * 64 + lane]) + b2f(hWlb[(size_t)s3 * 64 + lane]);
    }
    for (; j < deg; j++) a += b2f(hWlb[(size_t)adj[start + j] * 64 + lane]);
    out[(size_t)node * 64 + lane] += a / fmaxf((float)deg, 1.0f);
}

// ---------------------------------------------------------------------------
extern "C" void kernel_launch(void* const* d_in, const int* in_sizes, int n_in,
                              void* d_out, int out_size, void* d_ws, size_t ws_size,
                              hipStream_t stream) {
    const float* x    = (const float*)d_in[0];
    const float* Wl   = (const float*)d_in[1];
    const float* bl   = (const float*)d_in[2];
    const float* Wr   = (const float*)d_in[3];
    const float* Wl_f = (const float*)d_in[4];
    const float* bl_f = (const float*)d_in[5];
    const float* Wr_f = (const float*)d_in[6];
    const int* ei0 = (const int*)d_in[7];
    const int* ei1 = (const int*)d_in[8];
    const int* ei2 = (const int*)d_in[9];
    float* out = (float*)d_out;

    // workspace layout, total ~60 MB (well inside proven >=123 MB budget)
    char* ws = (char*)d_ws;
    int* cnt               = (int*)(ws);                                   // 1.2 MB
    int* cursor            = (int*)(ws + ((size_t)2  << 20));              // 1.2 MB
    int* rowstart          = (int*)(ws + ((size_t)4  << 20));              // 1.2 MB
    int* blocksum          = (int*)(ws + ((size_t)6  << 20));              // 1.2 KB
    unsigned short* Wfrag  = (unsigned short*)(ws + ((size_t)7  << 20));   // 192 KB
    unsigned short* Wfrag2 = (unsigned short*)(ws + ((size_t)15 << 19));   // 32 KB
    int* adj               = (int*)(ws + ((size_t)8  << 20));              // 7.2 MB
    unsigned short* xb     = (unsigned short*)(ws + ((size_t)16 << 20));   // 25.6 MB
    unsigned short* hWlb   = (unsigned short*)(ws + ((size_t)42 << 20));   // 12.8 MB

    hipMemsetAsync(cnt, 0, 3 * N_NODES * sizeof(int), stream);

    dim3 ge((N_EDGES + 255) / 256, 3);
    count_kernel<<<ge, 256, 0, stream>>>(ei0, ei1, ei2, cnt);
    scan1_kernel<<<dim3(NCHUNK, 3), 1024, 0, stream>>>(cnt, rowstart, blocksum);
    scan2_kernel<<<1, 128, 0, stream>>>(blocksum);
    scan3_kernel<<<dim3(392, 3), 256, 0, stream>>>(rowstart, blocksum, cursor);
    fill_kernel<<<ge, 256, 0, stream>>>(ei0, ei1, ei2, cursor, adj);
    wprep_kernel<<<448, 256, 0, stream>>>(Wl, Wr, Wl_f, Wr_f, Wfrag, Wfrag2);
    xcast_kernel<<<(N_NODES * 128 / 8) / 256, 256, 0, stream>>>(x, xb);

    const int TILE_BLOCKS = (N_NODES + 63) / 64;   // 1563
    mega2_kernel<<<TILE_BLOCKS, 256, 0, stream>>>(
        xb, adj, rowstart, cnt, Wfrag, bl, Wfrag2, bl_f, hWlb, out);

    const int GATHER_BLOCKS = (N_NODES + 3) / 4;   // one wave per node
    gather64_kernel<<<GATHER_BLOCKS, 256, 0, stream>>>(hWlb, adj, rowstart, cnt, out);
}

// Round 6
// 562.180 us; speedup vs baseline: 1.0613x; 1.0613x over previous
//
#include <hip/hip_runtime.h>

#define N_NODES 100000
#define N_EDGES 600000
#define NCHUNK 98            // ceil(100000/1024)
#define LDS_STRIDE 136       // ushorts per row: 128 + 8 pad

typedef __attribute__((ext_vector_type(8))) short short8;
typedef __attribute__((ext_vector_type(4))) float f32x4;
typedef __attribute__((ext_vector_type(8))) unsigned short ushort8v;

__device__ __forceinline__ unsigned short f2b(float f) {   // fp32 -> bf16 RNE
    unsigned u = __builtin_bit_cast(unsigned, f);
    return (unsigned short)((u + 0x7fffu + ((u >> 16) & 1u)) >> 16);
}
__device__ __forceinline__ float b2f(unsigned short b) {
    return __builtin_bit_cast(float, (unsigned)b << 16);
}

// ---------------------------------------------------------------------------
__global__ void count_kernel(const int* __restrict__ e0, const int* __restrict__ e1,
                             const int* __restrict__ e2, int* __restrict__ cnt) {
    int e = blockIdx.x * blockDim.x + threadIdx.x;
    if (e >= N_EDGES) return;
    int r = blockIdx.y;
    const int* ei = (r == 0) ? e0 : (r == 1 ? e1 : e2);
    atomicAdd(&cnt[r * N_NODES + ei[N_EDGES + e]], 1);
}

// ---------------------------------------------------------------------------
__global__ __launch_bounds__(1024) void scan1_kernel(const int* __restrict__ cnt,
                                                     int* __restrict__ rowstart,
                                                     int* __restrict__ blocksum) {
    int r = blockIdx.y;
    int tid = threadIdx.x, lane = tid & 63, wid = tid >> 6;
    int i = blockIdx.x * 1024 + tid;
    __shared__ int wsum[16];
    int v = (i < N_NODES) ? cnt[r * N_NODES + i] : 0;
    int incl = v;
#pragma unroll
    for (int off = 1; off < 64; off <<= 1) {
        int t = __shfl_up(incl, off);
        if (lane >= off) incl += t;
    }
    if (lane == 63) wsum[wid] = incl;
    __syncthreads();
    if (wid == 0) {
        int wv = (lane < 16) ? wsum[lane] : 0;
#pragma unroll
        for (int off = 1; off < 16; off <<= 1) {
            int t = __shfl_up(wv, off);
            if (lane >= off) wv += t;
        }
        if (lane < 16) wsum[lane] = wv;
    }
    __syncthreads();
    int woff = (wid > 0) ? wsum[wid - 1] : 0;
    if (i < N_NODES) rowstart[r * N_NODES + i] = woff + incl - v;
    if (tid == 0) blocksum[r * NCHUNK + blockIdx.x] = wsum[15];
}

__global__ __launch_bounds__(128) void scan2_kernel(int* __restrict__ blocksum) {
    __shared__ int s[3 * NCHUNK];
    int tid = threadIdx.x;
    for (int i = tid; i < 3 * NCHUNK; i += 128) s[i] = blocksum[i];
    __syncthreads();
    if (tid < 3) {
        int run = 0;
        for (int j = 0; j < NCHUNK; j++) { int t = s[tid * NCHUNK + j]; s[tid * NCHUNK + j] = run; run += t; }
    }
    __syncthreads();
    for (int i = tid; i < 3 * NCHUNK; i += 128) blocksum[i] = s[i];
}

// Phase 3: add block offsets; also seed cursor = rowstart (absolute positions).
__global__ void scan3_kernel(int* __restrict__ rowstart, const int* __restrict__ blocksum,
                             int* __restrict__ cursor) {
    int r = blockIdx.y;
    int i = blockIdx.x * 256 + threadIdx.x;
    if (i < N_NODES) {
        int v = rowstart[r * N_NODES + i] + blocksum[r * NCHUNK + (i >> 10)];
        rowstart[r * N_NODES + i] = v;
        cursor[r * N_NODES + i] = v;
    }
}

// ---------------------------------------------------------------------------
// CSR fill: cursor holds absolute write positions (seeded from rowstart).
__global__ void fill_kernel(const int* __restrict__ e0, const int* __restrict__ e1,
                            const int* __restrict__ e2,
                            int* __restrict__ cursor, int* __restrict__ adj) {
    int e = blockIdx.x * blockDim.x + threadIdx.x;
    if (e >= N_EDGES) return;
    int r = blockIdx.y;
    const int* ei = (r == 0) ? e0 : (r == 1 ? e1 : e2);
    int src = ei[e], dst = ei[N_EDGES + e];
    int pos = atomicAdd(&cursor[r * N_NODES + dst], 1);
    adj[(size_t)r * N_EDGES + pos] = src;
}

// ---------------------------------------------------------------------------
// x (fp32) -> xb (bf16), 8 elems/thread.
__global__ void xcast_kernel(const float* __restrict__ x, unsigned short* __restrict__ xb) {
    int idx = blockIdx.x * 256 + threadIdx.x;
    const float4* p = (const float4*)x + (size_t)idx * 2;
    float4 a = p[0], b = p[1];
    ushort8v o;
    o[0] = f2b(a.x); o[1] = f2b(a.y); o[2] = f2b(a.z); o[3] = f2b(a.w);
    o[4] = f2b(b.x); o[5] = f2b(b.y); o[6] = f2b(b.z); o[7] = f2b(b.w);
    *(ushort8v*)(xb + (size_t)idx * 8) = o;
}

// ---------------------------------------------------------------------------
// Pre-swizzle weights into MFMA B-fragment order (coalesced lane*16B bursts).
__global__ void wprep_kernel(const float* __restrict__ Wl, const float* __restrict__ Wr,
                             const float* __restrict__ Wl_f, const float* __restrict__ Wr_f,
                             unsigned short* __restrict__ Wfrag, unsigned short* __restrict__ Wfrag2) {
    int idx = blockIdx.x * 256 + threadIdx.x;      // 448 blocks = 114688 threads
    int j = idx & 7, lane = (idx >> 3) & 63;
    int quad = lane >> 4, l16 = lane & 15;
    if (idx < 98304) {
        int t = (idx >> 9) & 1, s = (idx >> 10) & 7, w = (idx >> 13) & 3, r = idx >> 15;
        int k = s * 32 + quad * 8 + j;
        int n = w * 32 + t * 16 + l16;
        float v = (k < 128) ? Wl[((size_t)r * 128 + k) * 128 + n]
                            : Wr[((size_t)r * 128 + (k - 128)) * 128 + n];
        Wfrag[idx] = f2b(v);
    } else {
        int i2 = idx - 98304;
        if (i2 < 16384) {
            int t = (i2 >> 9) & 1, s = (i2 >> 10) & 3, w = (i2 >> 12) & 3;
            int k = s * 32 + quad * 8 + j;
            int n = w * 32 + t * 16 + l16;
            float v = (n < 64) ? Wl_f[(size_t)k * 64 + n] : Wr_f[(size_t)k * 64 + (n - 64)];
            Wfrag2[i2] = f2b(v);
        }
    }
}

// ---------------------------------------------------------------------------
// Gather-mean, 128 bf16 channels (256 B rows). One wave per node; 16 lanes
// per row (ushort8 = 16 B/lane), so 4 edge rows in flight per load batch,
// unrolled x2 = 8 rows in flight. Butterfly-reduce across subwaves at end.
__global__ void gather128_kernel(const unsigned short* __restrict__ xb, const int* __restrict__ adj,
                                 const int* __restrict__ rowstart, const int* __restrict__ cnt,
                                 unsigned short* __restrict__ aggb) {
    int node = (blockIdx.x * blockDim.x + threadIdx.x) >> 6;
    int lane = threadIdx.x & 63;
    if (node >= N_NODES) return;
    int sub = lane >> 4, l16 = lane & 15;
    int start = rowstart[node];
    int deg = cnt[node];
    float acc[8];
#pragma unroll
    for (int i = 0; i < 8; i++) acc[i] = 0.f;
    int j = sub;
    for (; j + 4 < deg; j += 8) {          // this subwave: edges j, j+4
        int s0 = adj[start + j];
        int s1 = adj[start + j + 4];
        ushort8v v0 = *(const ushort8v*)(xb + (size_t)s0 * 128 + l16 * 8);
        ushort8v v1 = *(const ushort8v*)(xb + (size_t)s1 * 128 + l16 * 8);
#pragma unroll
        for (int i = 0; i < 8; i++) acc[i] += b2f(v0[i]) + b2f(v1[i]);
    }
    if (j < deg) {
        int s0 = adj[start + j];
        ushort8v v0 = *(const ushort8v*)(xb + (size_t)s0 * 128 + l16 * 8);
#pragma unroll
        for (int i = 0; i < 8; i++) acc[i] += b2f(v0[i]);
    }
#pragma unroll
    for (int i = 0; i < 8; i++) {          // reduce over lane bits 4,5
        acc[i] += __shfl_xor(acc[i], 16);
        acc[i] += __shfl_xor(acc[i], 32);
    }
    if (sub == 0) {
        float inv = 1.0f / fmaxf((float)deg, 1.0f);
        ushort8v o;
#pragma unroll
        for (int i = 0; i < 8; i++) o[i] = f2b(acc[i] * inv);
        *(ushort8v*)(aggb + (size_t)node * 128 + l16 * 8) = o;   // 16 lanes x 16 B
    }
}

// ---------------------------------------------------------------------------
// Layer-1 for one relation: hb (+)= relu([agg|x](K=256) @ W + bl) / 3  (bf16 RMW)
// 64 rows x 128 cols per block; wave w owns cols [w*32, w*32+32).
__global__ __launch_bounds__(256, 4) void layer1_kernel(
    const unsigned short* __restrict__ aggb, const unsigned short* __restrict__ xb,
    const unsigned short* __restrict__ Wfrag, const float* __restrict__ bl,
    unsigned short* __restrict__ hb, int first) {
    __shared__ unsigned short s_a[64 * LDS_STRIDE];
    __shared__ unsigned short s_x[64 * LDS_STRIDE];
    int tid = threadIdx.x, wave = tid >> 6, lane = tid & 63;
    int quad = lane >> 4, l16 = lane & 15;
    int rowbase = blockIdx.x * 64;

#pragma unroll
    for (int it = 0; it < 4; it++) {
        int idx = tid + it * 256;
        int row = idx >> 4, c = idx & 15;
        int grow = rowbase + row;
        short8 xv = {0, 0, 0, 0, 0, 0, 0, 0};
        if (grow < N_NODES) xv = *(const short8*)(xb + (size_t)grow * 128 + c * 8);
        *(short8*)&s_x[row * LDS_STRIDE + c * 8] = xv;
        short8 av = *(const short8*)(aggb + (size_t)(rowbase + row) * 128 + c * 8);
        *(short8*)&s_a[row * LDS_STRIDE + c * 8] = av;
    }
    __syncthreads();

    f32x4 acc[4][2];
#pragma unroll
    for (int g = 0; g < 4; g++) { acc[g][0] = (f32x4){0.f,0.f,0.f,0.f}; acc[g][1] = (f32x4){0.f,0.f,0.f,0.f}; }

    const unsigned short* W = Wfrag + wave * 8192;
#pragma unroll
    for (int s = 0; s < 8; s++) {
        short8 bf0 = *(const short8*)(W + s * 1024 + lane * 8);         // coalesced 1KB
        short8 bf1 = *(const short8*)(W + s * 1024 + 512 + lane * 8);
        const unsigned short* src = (s < 4) ? s_a : s_x;
        int ko = (s & 3) * 32 + quad * 8;
#pragma unroll
        for (int g = 0; g < 4; g++) {
            short8 af = *(const short8*)&src[(g * 16 + l16) * LDS_STRIDE + ko];
            acc[g][0] = __builtin_amdgcn_mfma_f32_16x16x32_bf16(af, bf0, acc[g][0], 0, 0, 0);
            acc[g][1] = __builtin_amdgcn_mfma_f32_16x16x32_bf16(af, bf1, acc[g][1], 0, 0, 0);
        }
    }

    float b0 = bl[wave * 32 + l16];
    float b1 = bl[wave * 32 + 16 + l16];
#pragma unroll
    for (int g = 0; g < 4; g++)
#pragma unroll
        for (int t = 0; t < 2; t++) {
            float bb = t ? b1 : b0;
            int col = wave * 32 + t * 16 + l16;
#pragma unroll
            for (int q = 0; q < 4; q++) {
                int row = rowbase + g * 16 + quad * 4 + q;
                if (row < N_NODES) {
                    float v = fmaxf(acc[g][t][q] + bb, 0.f) * (1.0f / 3.0f);
                    size_t o = (size_t)row * 128 + col;
                    if (!first) v += b2f(hb[o]);
                    hb[o] = f2b(v);
                }
            }
        }
}

// ---------------------------------------------------------------------------
// Layer-2: [hWl|hWr] = h @ Wf2 (K=128); hWl -> bf16 buffer, out = hWr + bl_f.
__global__ __launch_bounds__(256, 4) void layer2_kernel(
    const unsigned short* __restrict__ hb, const unsigned short* __restrict__ Wfrag2,
    const float* __restrict__ bl_f, unsigned short* __restrict__ hWlb,
    float* __restrict__ out) {
    __shared__ unsigned short s_h[64 * LDS_STRIDE];
    int tid = threadIdx.x, wave = tid >> 6, lane = tid & 63;
    int quad = lane >> 4, l16 = lane & 15;
    int rowbase = blockIdx.x * 64;

#pragma unroll
    for (int it = 0; it < 4; it++) {
        int idx = tid + it * 256;
        int row = idx >> 4, c = idx & 15;
        int grow = rowbase + row;
        short8 hv = {0, 0, 0, 0, 0, 0, 0, 0};
        if (grow < N_NODES) hv = *(const short8*)(hb + (size_t)grow * 128 + c * 8);
        *(short8*)&s_h[row * LDS_STRIDE + c * 8] = hv;
    }
    __syncthreads();

    f32x4 acc[4][2];
#pragma unroll
    for (int g = 0; g < 4; g++) { acc[g][0] = (f32x4){0.f,0.f,0.f,0.f}; acc[g][1] = (f32x4){0.f,0.f,0.f,0.f}; }

    const unsigned short* W = Wfrag2 + wave * 4096;
#pragma unroll
    for (int s = 0; s < 4; s++) {
        short8 bf0 = *(const short8*)(W + s * 1024 + lane * 8);
        short8 bf1 = *(const short8*)(W + s * 1024 + 512 + lane * 8);
        int ko = s * 32 + quad * 8;
#pragma unroll
        for (int g = 0; g < 4; g++) {
            short8 af = *(const short8*)&s_h[(g * 16 + l16) * LDS_STRIDE + ko];
            acc[g][0] = __builtin_amdgcn_mfma_f32_16x16x32_bf16(af, bf0, acc[g][0], 0, 0, 0);
            acc[g][1] = __builtin_amdgcn_mfma_f32_16x16x32_bf16(af, bf1, acc[g][1], 0, 0, 0);
        }
    }

#pragma unroll
    for (int g = 0; g < 4; g++)
#pragma unroll
        for (int t = 0; t < 2; t++) {
            int col = wave * 32 + t * 16 + l16;
#pragma unroll
            for (int q = 0; q < 4; q++) {
                int row = rowbase + g * 16 + quad * 4 + q;
                if (row < N_NODES) {
                    if (col < 64) hWlb[(size_t)row * 64 + col] = f2b(acc[g][t][q]);
                    else out[(size_t)row * 64 + (col - 64)] = acc[g][t][q] + bl_f[col - 64];
                }
            }
        }
}

// ---------------------------------------------------------------------------
// Gather-mean of hWl (bf16, 64 ch = 128 B rows) + add into out.
// 8 lanes per row (ushort8), 8 rows in flight per batch, x2 unroll.
__global__ void gather64_kernel(const unsigned short* __restrict__ hWlb, const int* __restrict__ adj,
                                const int* __restrict__ rowstart, const int* __restrict__ cnt,
                                float* __restrict__ out) {
    int node = (blockIdx.x * blockDim.x + threadIdx.x) >> 6;
    int lane = threadIdx.x & 63;
    if (node >= N_NODES) return;
    int sub = lane >> 3, l8 = lane & 7;
    int start = rowstart[node];
    int deg = cnt[node];
    float acc[8];
#pragma unroll
    for (int i = 0; i < 8; i++) acc[i] = 0.f;
    int j = sub;
    for (; j + 8 < deg; j += 16) {         // this subwave: edges j, j+8
        int s0 = adj[start + j];
        int s1 = adj[start + j + 8];
        ushort8v v0 = *(const ushort8v*)(hWlb + (size_t)s0 * 64 + l8 * 8);
        ushort8v v1 = *(const ushort8v*)(hWlb + (size_t)s1 * 64 + l8 * 8);
#pragma unroll
        for (int i = 0; i < 8; i++) acc[i] += b2f(v0[i]) + b2f(v1[i]);
    }
    if (j < deg) {
        int s0 = adj[start + j];
        ushort8v v0 = *(const ushort8v*)(hWlb + (size_t)s0 * 64 + l8 * 8);
#pragma unroll
        for (int i = 0; i < 8; i++) acc[i] += b2f(v0[i]);
    }
#pragma unroll
    for (int i = 0; i < 8; i++) {          // reduce over lane bits 3,4,5
        acc[i] += __shfl_xor(acc[i], 8);
        acc[i] += __shfl_xor(acc[i], 16);
        acc[i] += __shfl_xor(acc[i], 32);
    }
    if (sub == 0) {
        float inv = 1.0f / fmaxf((float)deg, 1.0f);
        float4* po = (float4*)(out + (size_t)node * 64 + l8 * 8);
        float4 a = po[0], b = po[1];
        a.x += acc[0] * inv; a.y += acc[1] * inv; a.z += acc[2] * inv; a.w += acc[3] * inv;
        b.x += acc[4] * inv; b.y += acc[5] * inv; b.z += acc[6] * inv; b.w += acc[7] * inv;
        po[0] = a; po[1] = b;
    }
}

// ---------------------------------------------------------------------------
extern "C" void kernel_launch(void* const* d_in, const int* in_sizes, int n_in,
                              void* d_out, int out_size, void* d_ws, size_t ws_size,
                              hipStream_t stream) {
    const float* x    = (const float*)d_in[0];
    const float* Wl   = (const float*)d_in[1];
    const float* bl   = (const float*)d_in[2];
    const float* Wr   = (const float*)d_in[3];
    const float* Wl_f = (const float*)d_in[4];
    const float* bl_f = (const float*)d_in[5];
    const float* Wr_f = (const float*)d_in[6];
    const int* ei0 = (const int*)d_in[7];
    const int* ei1 = (const int*)d_in[8];
    const int* ei2 = (const int*)d_in[9];
    float* out = (float*)d_out;

    // workspace layout, total ~107 MB
    char* ws = (char*)d_ws;
    int* cnt               = (int*)(ws);                                   // 1.2 MB
    int* cursor            = (int*)(ws + ((size_t)2  << 20));              // 1.2 MB
    int* rowstart          = (int*)(ws + ((size_t)4  << 20));              // 1.2 MB
    int* blocksum          = (int*)(ws + ((size_t)6  << 20));              // 1.2 KB
    unsigned short* Wfrag  = (unsigned short*)(ws + ((size_t)7  << 20));   // 192 KB
    unsigned short* Wfrag2 = (unsigned short*)(ws + ((size_t)15 << 19));   // 32 KB
    int* adj               = (int*)(ws + ((size_t)8  << 20));              // 7.2 MB
    unsigned short* xb     = (unsigned short*)(ws + ((size_t)16 << 20));   // 25.6 MB
    unsigned short* aggb   = (unsigned short*)(ws + ((size_t)42 << 20));   // 25.6 MB
    unsigned short* hb     = (unsigned short*)(ws + ((size_t)68 << 20));   // 25.6 MB
    unsigned short* hWlb   = (unsigned short*)(ws + ((size_t)94 << 20));   // 12.8 MB

    hipMemsetAsync(cnt, 0, 3 * N_NODES * sizeof(int), stream);

    dim3 ge((N_EDGES + 255) / 256, 3);
    count_kernel<<<ge, 256, 0, stream>>>(ei0, ei1, ei2, cnt);
    scan1_kernel<<<dim3(NCHUNK, 3), 1024, 0, stream>>>(cnt, rowstart, blocksum);
    scan2_kernel<<<1, 128, 0, stream>>>(blocksum);
    scan3_kernel<<<dim3(392, 3), 256, 0, stream>>>(rowstart, blocksum, cursor);
    fill_kernel<<<ge, 256, 0, stream>>>(ei0, ei1, ei2, cursor, adj);
    wprep_kernel<<<448, 256, 0, stream>>>(Wl, Wr, Wl_f, Wr_f, Wfrag, Wfrag2);
    xcast_kernel<<<(N_NODES * 128 / 8) / 256, 256, 0, stream>>>(x, xb);

    const int GATHER_BLOCKS = (N_NODES + 3) / 4;   // one wave per node
    const int TILE_BLOCKS = (N_NODES + 63) / 64;   // 1563
    for (int r = 0; r < 3; r++) {
        gather128_kernel<<<GATHER_BLOCKS, 256, 0, stream>>>(
            xb, adj + (size_t)r * N_EDGES, rowstart + r * N_NODES, cnt + r * N_NODES, aggb);
        layer1_kernel<<<TILE_BLOCKS, 256, 0, stream>>>(
            aggb, xb, Wfrag + (size_t)r * 32768, bl + r * 128, hb, r == 0 ? 1 : 0);
    }

    layer2_kernel<<<TILE_BLOCKS, 256, 0, stream>>>(hb, Wfrag2, bl_f, hWlb, out);
    gather64_kernel<<<GATHER_BLOCKS, 256, 0, stream>>>(hWlb, adj, rowstart, cnt, out);
}